// Round 4
// baseline (335.576 us; speedup 1.0000x reference)
//
#include <hip/hip_runtime.h>

// Problem constants
#define BB 8
#define TT 1024
#define EE 256
#define HH 8
#define BH 64           // BB*HH
#define MM 8192         // BB*TT
#define NQKV 2048       // HH*EE

typedef __attribute__((ext_vector_type(8))) short bf16x8;
typedef __attribute__((ext_vector_type(4))) float f32x4;

__device__ __forceinline__ unsigned short f2bf(float f) {
  unsigned int u = __float_as_uint(f);
  u += 0x7fff + ((u >> 16) & 1);   // RNE
  return (unsigned short)(u >> 16);
}

// ---------------- prep kernels ----------------
__global__ void k_convert_x(const float4* __restrict__ x, ushort4* __restrict__ xb, int n4) {
  int i = blockIdx.x * 256 + threadIdx.x;
  if (i < n4) {
    float4 f = x[i];
    ushort4 o;
    o.x = f2bf(f.x); o.y = f2bf(f.y); o.z = f2bf(f.z); o.w = f2bf(f.w);
    xb[i] = o;
  }
}

// in: K x N (f32, row-major) -> out: N x K (bf16, row-major), scaled
__global__ void k_transpose_w(const float* __restrict__ in, unsigned short* __restrict__ out,
                              int K, int N, float scale) {
  __shared__ float tile[32][33];
  int n0 = blockIdx.x * 32, k0 = blockIdx.y * 32;
  int tx = threadIdx.x & 31, ty = threadIdx.x >> 5;
#pragma unroll
  for (int p = 0; p < 4; p++) tile[ty + 8 * p][tx] = in[(size_t)(k0 + ty + 8 * p) * N + (n0 + tx)];
  __syncthreads();
#pragma unroll
  for (int p = 0; p < 4; p++)
    out[(size_t)(n0 + ty + 8 * p) * K + (k0 + tx)] = f2bf(scale * tile[tx][ty + 8 * p]);
}

// ---------------- QKV GEMM ----------------
// A = xb (8192x256 bf16), B = Wt* (2048x256 bf16, N-major)
// q,k out -> [b][h][t][d] bf16 ; v out -> [b][h][d][t] bf16 (transposed in-epilogue)
__global__ __launch_bounds__(256) void k_gemm_qkv(
    const unsigned short* __restrict__ xb,
    const unsigned short* __restrict__ Wtq,
    const unsigned short* __restrict__ Wtk,
    const unsigned short* __restrict__ Wtv,
    unsigned short* __restrict__ qo,
    unsigned short* __restrict__ ko,
    unsigned short* __restrict__ vto) {
  __shared__ unsigned short sh[2 * 128 * 72];
  unsigned short* As = sh;
  unsigned short* Bs = sh + 128 * 72;
  const unsigned short* Bw = (blockIdx.z == 0) ? Wtq : (blockIdx.z == 1 ? Wtk : Wtv);
  int tid = threadIdx.x, lane = tid & 63, w = tid >> 6;
  int wr = w >> 1, wc = w & 1;
  int m0 = blockIdx.y * 128, n0 = blockIdx.x * 128;
  f32x4 acc[4][4] = {};
  for (int kt = 0; kt < 4; kt++) {
    __syncthreads();
    const unsigned short* ga = xb + (size_t)m0 * 256 + kt * 64;
    const unsigned short* gb = Bw + (size_t)n0 * 256 + kt * 64;
#pragma unroll
    for (int p = 0; p < 4; p++) {
      int c = p * 256 + tid, row = c >> 3, col = (c & 7) * 8;
      *(bf16x8*)&As[row * 72 + col] = *(const bf16x8*)&ga[(size_t)row * 256 + col];
      *(bf16x8*)&Bs[row * 72 + col] = *(const bf16x8*)&gb[(size_t)row * 256 + col];
    }
    __syncthreads();
#pragma unroll
    for (int kk = 0; kk < 2; kk++) {
      bf16x8 af[4], bfr[4];
#pragma unroll
      for (int mi = 0; mi < 4; mi++)
        af[mi] = *(bf16x8*)&As[(wr * 64 + mi * 16 + (lane & 15)) * 72 + kk * 32 + (lane >> 4) * 8];
#pragma unroll
      for (int ni = 0; ni < 4; ni++)
        bfr[ni] = *(bf16x8*)&Bs[(wc * 64 + ni * 16 + (lane & 15)) * 72 + kk * 32 + (lane >> 4) * 8];
#pragma unroll
      for (int mi = 0; mi < 4; mi++)
#pragma unroll
        for (int ni = 0; ni < 4; ni++)
          acc[mi][ni] = __builtin_amdgcn_mfma_f32_16x16x32_bf16(af[mi], bfr[ni], acc[mi][ni], 0, 0, 0);
    }
  }
  // LDS-bounce epilogue; per-wave 64x72 region
  __syncthreads();
  unsigned short* ob = sh + w * (64 * 72);
  int gm0 = m0 + wr * 64, gn0 = n0 + wc * 64;
  int bb = gm0 >> 10, t0 = gm0 & 1023, hh = gn0 >> 8, d0 = gn0 & 255;
  if (blockIdx.z != 2) {
    // row-major [t][d] bounce, coalesced stores into [bh][t][d]
#pragma unroll
    for (int mi = 0; mi < 4; mi++)
#pragma unroll
      for (int ni = 0; ni < 4; ni++)
#pragma unroll
        for (int i = 0; i < 4; i++)
          ob[(mi * 16 + (lane >> 4) * 4 + i) * 72 + ni * 16 + (lane & 15)] = f2bf(acc[mi][ni][i]);
    unsigned short* outp = (blockIdx.z == 0) ? qo : ko;
    unsigned short* dst = outp + ((size_t)(bb * HH + hh) * TT + t0) * EE + d0;
#pragma unroll
    for (int p = 0; p < 8; p++) {
      int row = (lane >> 3) + 8 * p, col = (lane & 7) * 8;
      *(bf16x8*)&dst[(size_t)row * EE + col] = *(bf16x8*)&ob[row * 72 + col];
    }
  } else {
    // transposed [d][t] bounce, coalesced stores into [bh][d][t]
#pragma unroll
    for (int mi = 0; mi < 4; mi++)
#pragma unroll
      for (int ni = 0; ni < 4; ni++)
#pragma unroll
        for (int i = 0; i < 4; i++)
          ob[(ni * 16 + (lane & 15)) * 72 + mi * 16 + (lane >> 4) * 4 + i] = f2bf(acc[mi][ni][i]);
    unsigned short* dst = vto + ((size_t)(bb * HH + hh) * EE + d0) * TT + t0;
#pragma unroll
    for (int p = 0; p < 8; p++) {
      int row = (lane >> 3) + 8 * p, col = (lane & 7) * 8;   // row=d_local, col=t_local
      *(bf16x8*)&dst[(size_t)row * TT + col] = *(bf16x8*)&ob[row * 72 + col];
    }
  }
}

// ---------------- flash attention ----------------
// q,k: [bh][t][d] bf16 (pre-scaled), vt: [bh][d][t] bf16, mask: [b][t] int
// ao: [b][t][h*256+d] bf16
// 1D grid of 1024 blocks, XCD-swizzled so the 16 q-tiles of each bh share an XCD L2.
__global__ __launch_bounds__(256, 2) void k_flash(
    const unsigned short* __restrict__ q,
    const unsigned short* __restrict__ k,
    const unsigned short* __restrict__ vt,
    const int* __restrict__ mask,
    unsigned short* __restrict__ ao) {
  __shared__ unsigned short Ks[64 * 264];
  __shared__ unsigned short Vs[256 * 72];
  __shared__ unsigned short Ps[4 * 16 * 72];
  int tid = threadIdx.x, lane = tid & 63, w = tid >> 6;
  // bijective XCD swizzle: 1024 blocks, 8 XCDs, 128 per XCD
  int L = blockIdx.x;
  int wg = (L & 7) * 128 + (L >> 3);
  int qt = wg & 15, bh = wg >> 4;
  int b = bh >> 3, hh = bh & 7;
  const unsigned short* qbase = q + ((size_t)bh * TT + qt * 64) * EE;
  const unsigned short* kbase = k + (size_t)bh * TT * EE;
  const unsigned short* vbase = vt + (size_t)bh * EE * TT;

  // stage Q tile through Ks, pull A-fragments to registers
#pragma unroll
  for (int p = 0; p < 8; p++) {
    int c = p * 256 + tid, row = c >> 5, col = (c & 31) * 8;
    *(bf16x8*)&Ks[row * 264 + col] = *(const bf16x8*)&qbase[(size_t)row * EE + col];
  }
  __syncthreads();
  bf16x8 qr[8];
#pragma unroll
  for (int kk = 0; kk < 8; kk++)
    qr[kk] = *(bf16x8*)&Ks[(w * 16 + (lane & 15)) * 264 + kk * 32 + (lane >> 4) * 8];

  int mq[4];
#pragma unroll
  for (int i = 0; i < 4; i++)
    mq[i] = mask[b * TT + qt * 64 + w * 16 + (lane >> 4) * 4 + i];

  float mrow[4], lrow[4];
  f32x4 oacc[16] = {};
#pragma unroll
  for (int i = 0; i < 4; i++) { mrow[i] = -1e30f; lrow[i] = 0.0f; }

  for (int kt = 0; kt < 16; kt++) {
    __syncthreads();
    // stage K tile [64][256] -> Ks (padded 264)
#pragma unroll
    for (int p = 0; p < 8; p++) {
      int c = p * 256 + tid, row = c >> 5, col = (c & 31) * 8;
      *(bf16x8*)&Ks[row * 264 + col] = *(const bf16x8*)&kbase[((size_t)(kt * 64 + row)) * EE + col];
    }
    // stage Vt tile [256][64] -> Vs (padded 72)
#pragma unroll
    for (int p = 0; p < 8; p++) {
      int c = p * 256 + tid, d = c >> 3, col = (c & 7) * 8;
      *(bf16x8*)&Vs[d * 72 + col] = *(const bf16x8*)&vbase[(size_t)d * TT + kt * 64 + col];
    }
    __syncthreads();

    // S = Q K^T  (per wave: 16 x 64)
    f32x4 sacc[4] = {};
#pragma unroll
    for (int kk = 0; kk < 8; kk++) {
#pragma unroll
      for (int fc = 0; fc < 4; fc++) {
        bf16x8 bfr = *(bf16x8*)&Ks[(fc * 16 + (lane & 15)) * 264 + kk * 32 + (lane >> 4) * 8];
        sacc[fc] = __builtin_amdgcn_mfma_f32_16x16x32_bf16(qr[kk], bfr, sacc[fc], 0, 0, 0);
      }
    }

    // mask + online softmax (defer-max, THR=8)
    int msv[4];
#pragma unroll
    for (int fc = 0; fc < 4; fc++) msv[fc] = mask[b * TT + kt * 64 + fc * 16 + (lane & 15)];
    float pv[4][4], rmax[4];
#pragma unroll
    for (int i = 0; i < 4; i++) rmax[i] = -1e30f;
#pragma unroll
    for (int fc = 0; fc < 4; fc++)
#pragma unroll
      for (int i = 0; i < 4; i++) {
        float s = (mq[i] && msv[fc]) ? sacc[fc][i] : -1e30f;
        pv[fc][i] = s;
        rmax[i] = fmaxf(rmax[i], s);
      }
#pragma unroll
    for (int off = 1; off < 16; off <<= 1)
#pragma unroll
      for (int i = 0; i < 4; i++) rmax[i] = fmaxf(rmax[i], __shfl_xor(rmax[i], off));
    bool need = false;
#pragma unroll
    for (int i = 0; i < 4; i++) need |= (rmax[i] - mrow[i] > 8.0f);
    if (__any(need)) {
      float sc[4];
#pragma unroll
      for (int i = 0; i < 4; i++) {
        float mn = fmaxf(mrow[i], rmax[i]);
        sc[i] = __expf(mrow[i] - mn);
        mrow[i] = mn;
        lrow[i] *= sc[i];
      }
#pragma unroll
      for (int f = 0; f < 16; f++)
#pragma unroll
        for (int i = 0; i < 4; i++) oacc[f][i] *= sc[i];
    }
    float rsum[4] = {0.f, 0.f, 0.f, 0.f};
#pragma unroll
    for (int fc = 0; fc < 4; fc++)
#pragma unroll
      for (int i = 0; i < 4; i++) {
        float pe = __expf(pv[fc][i] - mrow[i]);
        pv[fc][i] = pe;
        rsum[i] += pe;
      }
#pragma unroll
    for (int off = 1; off < 16; off <<= 1)
#pragma unroll
      for (int i = 0; i < 4; i++) rsum[i] += __shfl_xor(rsum[i], off);
#pragma unroll
    for (int i = 0; i < 4; i++) lrow[i] += rsum[i];

    // P -> LDS (per-wave transpose buffer), then PV
    unsigned short* Pw = Ps + w * (16 * 72);
#pragma unroll
    for (int fc = 0; fc < 4; fc++)
#pragma unroll
      for (int i = 0; i < 4; i++)
        Pw[((lane >> 4) * 4 + i) * 72 + fc * 16 + (lane & 15)] = f2bf(pv[fc][i]);
#pragma unroll
    for (int kk2 = 0; kk2 < 2; kk2++) {
      bf16x8 pa = *(bf16x8*)&Pw[(lane & 15) * 72 + kk2 * 32 + (lane >> 4) * 8];
#pragma unroll
      for (int ff = 0; ff < 16; ff++) {
        bf16x8 vb = *(bf16x8*)&Vs[(ff * 16 + (lane & 15)) * 72 + kk2 * 32 + (lane >> 4) * 8];
        oacc[ff] = __builtin_amdgcn_mfma_f32_16x16x32_bf16(pa, vb, oacc[ff], 0, 0, 0);
      }
    }
  }

  // normalize + store via per-wave LDS bounce (coalesced 16B stores)
  float inv[4];
#pragma unroll
  for (int i = 0; i < 4; i++) inv[i] = 1.0f / lrow[i];
#pragma unroll
  for (int f = 0; f < 16; f++)
#pragma unroll
    for (int i = 0; i < 4; i++) oacc[f][i] *= inv[i];
  unsigned short* Pw = Ps + w * (16 * 72);
  int t0 = qt * 64 + w * 16;
#pragma unroll
  for (int c = 0; c < 4; c++) {
#pragma unroll
    for (int f4 = 0; f4 < 4; f4++) {
      int f = c * 4 + f4;
#pragma unroll
      for (int i = 0; i < 4; i++)
        Pw[((lane >> 4) * 4 + i) * 72 + f4 * 16 + (lane & 15)] = f2bf(oacc[f][i]);
    }
#pragma unroll
    for (int p = 0; p < 2; p++) {
      int row = lane >> 2, col = ((lane & 3) * 2 + p) * 8;
      bf16x8 vv = *(bf16x8*)&Pw[row * 72 + col];
      *(bf16x8*)&ao[((size_t)(b * TT + t0 + row)) * NQKV + hh * EE + c * 64 + col] = vv;
    }
  }
}

// ---------------- output GEMM ----------------
// A = ao (8192 x 2048 bf16), B = Wut (256 x 2048 bf16 N-major), out f32 + bias
__global__ __launch_bounds__(256) void k_gemm_out(
    const unsigned short* __restrict__ A,
    const unsigned short* __restrict__ Wut,
    const float* __restrict__ bu,
    float* __restrict__ out) {
  __shared__ unsigned short As[128 * 72];
  __shared__ unsigned short Bs[64 * 72];
  int tid = threadIdx.x, lane = tid & 63, w = tid >> 6;
  int wr = w >> 1, wc = w & 1;
  int m0 = blockIdx.y * 128, n0 = blockIdx.x * 64;
  f32x4 acc[4][2] = {};
  for (int kt = 0; kt < 32; kt++) {
    __syncthreads();
    const unsigned short* ga = A + (size_t)m0 * 2048 + kt * 64;
    const unsigned short* gb = Wut + (size_t)n0 * 2048 + kt * 64;
#pragma unroll
    for (int p = 0; p < 4; p++) {
      int c = p * 256 + tid, row = c >> 3, col = (c & 7) * 8;
      *(bf16x8*)&As[row * 72 + col] = *(const bf16x8*)&ga[(size_t)row * 2048 + col];
    }
#pragma unroll
    for (int p = 0; p < 2; p++) {
      int c = p * 256 + tid, row = c >> 3, col = (c & 7) * 8;
      *(bf16x8*)&Bs[row * 72 + col] = *(const bf16x8*)&gb[(size_t)row * 2048 + col];
    }
    __syncthreads();
#pragma unroll
    for (int kk = 0; kk < 2; kk++) {
      bf16x8 af[4], bfr[2];
#pragma unroll
      for (int mi = 0; mi < 4; mi++)
        af[mi] = *(bf16x8*)&As[(wr * 64 + mi * 16 + (lane & 15)) * 72 + kk * 32 + (lane >> 4) * 8];
#pragma unroll
      for (int ni = 0; ni < 2; ni++)
        bfr[ni] = *(bf16x8*)&Bs[(wc * 32 + ni * 16 + (lane & 15)) * 72 + kk * 32 + (lane >> 4) * 8];
#pragma unroll
      for (int mi = 0; mi < 4; mi++)
#pragma unroll
        for (int ni = 0; ni < 2; ni++)
          acc[mi][ni] = __builtin_amdgcn_mfma_f32_16x16x32_bf16(af[mi], bfr[ni], acc[mi][ni], 0, 0, 0);
    }
  }
#pragma unroll
  for (int mi = 0; mi < 4; mi++)
#pragma unroll
    for (int ni = 0; ni < 2; ni++) {
      int gm = m0 + wr * 64 + mi * 16 + (lane >> 4) * 4;
      int gn = n0 + wc * 32 + ni * 16 + (lane & 15);
      float bias = bu[gn];
#pragma unroll
      for (int i = 0; i < 4; i++)
        out[(size_t)(gm + i) * EE + gn] = acc[mi][ni][i] + bias;
    }
}

// ---------------- launch ----------------
extern "C" void kernel_launch(void* const* d_in, const int* in_sizes, int n_in,
                              void* d_out, int out_size, void* d_ws, size_t ws_size,
                              hipStream_t stream) {
  const float* x  = (const float*)d_in[0];
  const int* mask = (const int*)d_in[1];
  const float* Wq = (const float*)d_in[2];
  const float* Wk = (const float*)d_in[3];
  const float* Wv = (const float*)d_in[4];
  const float* Wu = (const float*)d_in[5];
  const float* bu = (const float*)d_in[6];
  float* out = (float*)d_out;

  char* ws = (char*)d_ws;
  size_t off = 0;
  auto alloc = [&](size_t bytes) {
    char* p = ws + off;
    off += (bytes + 255) & ~(size_t)255;
    return p;
  };
  unsigned short* xb  = (unsigned short*)alloc((size_t)MM * EE * 2);       // 4 MB
  unsigned short* Wtq = (unsigned short*)alloc((size_t)NQKV * EE * 2);     // 1 MB
  unsigned short* Wtk = (unsigned short*)alloc((size_t)NQKV * EE * 2);
  unsigned short* Wtv = (unsigned short*)alloc((size_t)NQKV * EE * 2);
  unsigned short* Wut = (unsigned short*)alloc((size_t)EE * NQKV * 2);
  unsigned short* qb  = (unsigned short*)alloc((size_t)BH * TT * EE * 2);  // 32 MB
  unsigned short* kb  = (unsigned short*)alloc((size_t)BH * TT * EE * 2);  // 32 MB
  unsigned short* vtb = (unsigned short*)alloc((size_t)BH * TT * EE * 2);  // 32 MB
  unsigned short* ao  = (unsigned short*)alloc((size_t)MM * NQKV * 2);     // 32 MB

  hipLaunchKernelGGL(k_convert_x, dim3((MM * EE / 4 + 255) / 256), dim3(256), 0, stream,
                     (const float4*)x, (ushort4*)xb, MM * EE / 4);
  // fold 1/e^0.25 = 0.25 into Wq and Wk
  hipLaunchKernelGGL(k_transpose_w, dim3(NQKV / 32, EE / 32), dim3(256), 0, stream, Wq, Wtq, EE, NQKV, 0.25f);
  hipLaunchKernelGGL(k_transpose_w, dim3(NQKV / 32, EE / 32), dim3(256), 0, stream, Wk, Wtk, EE, NQKV, 0.25f);
  hipLaunchKernelGGL(k_transpose_w, dim3(NQKV / 32, EE / 32), dim3(256), 0, stream, Wv, Wtv, EE, NQKV, 1.0f);
  hipLaunchKernelGGL(k_transpose_w, dim3(EE / 32, NQKV / 32), dim3(256), 0, stream, Wu, Wut, NQKV, EE, 1.0f);

  hipLaunchKernelGGL(k_gemm_qkv, dim3(NQKV / 128, MM / 128, 3), dim3(256), 0, stream,
                     xb, Wtq, Wtk, Wtv, qb, kb, vtb);
  hipLaunchKernelGGL(k_flash, dim3(TT / 64 * BH), dim3(256), 0, stream, qb, kb, vtb, mask, ao);
  hipLaunchKernelGGL(k_gemm_out, dim3(EE / 64, MM / 128), dim3(256), 0, stream, ao, Wut, bu, out);
}